// Round 17
// baseline (297.307 us; speedup 1.0000x reference)
//
#include <hip/hip_runtime.h>
#include <cstdint>

#define HEXP 10.0f
#define LN2 0.69314718056f
#define RLN2 1.44269504089f
#define QSCALE 500.0f

__device__ __forceinline__ float hw_log2(float x) { return __builtin_amdgcn_logf(x); }
__device__ __forceinline__ float hw_exp2(float x) { return __builtin_amdgcn_exp2f(x); }
__device__ __forceinline__ float hw_rcp(float x) { return __builtin_amdgcn_rcpf(x); }

typedef int i32x4 __attribute__((ext_vector_type(4)));

// ---- shared normalize+quantize helper (int8, x QSCALE) ----
// |xn_i| <= ~0.17 -> q <= ~87 << 127; dot exact in int32 (<= 7.7M < 2^24).
__device__ __forceinline__ int norm_quant(const float* in, int D, int row,
                                          int tid, float* s4) {
  const float4* inr = (const float4*)(in + (size_t)row * D);
  float4 v = inr[tid];
  float ss = v.x * v.x + v.y * v.y + v.z * v.z + v.w * v.w;
#pragma unroll
  for (int off = 32; off >= 1; off >>= 1) ss += __shfl_xor(ss, off, 64);
  if ((tid & 63) == 0) s4[tid >> 6] = ss;
  __syncthreads();
  float tot = s4[0] + s4[1] + s4[2] + s4[3];
  float scale = QSCALE / fmaxf(sqrtf(tot), 1e-12f);
  int q0 = __float2int_rn(fmaxf(-127.f, fminf(127.f, v.x * scale)));
  int q1 = __float2int_rn(fmaxf(-127.f, fminf(127.f, v.y * scale)));
  int q2 = __float2int_rn(fmaxf(-127.f, fminf(127.f, v.z * scale)));
  int q3 = __float2int_rn(fmaxf(-127.f, fminf(127.f, v.w * scale)));
  return (q0 & 0xff) | ((q1 & 0xff) << 8) | ((q2 & 0xff) << 16) | (q3 << 24);
}

// ------- rows -> FRAGMENT-MAJOR global layout (R15-verified transform) -------
// frag block (row>>4, k-tile) of 16 rows x 64 k stored contiguously (1KB):
// offset = (row>>4)*16*D + (k>>6)*1024 + ((k>>4)&3)*256 + (row&15)*16 + (k&15)
// -> a wave's MFMA operand (lane kq*16+fcol reads 16B) is one contiguous 1KB.
__global__ __launch_bounds__(256) void k_rownorm_fm(const float* __restrict__ in,
                                                    unsigned char* __restrict__ out,
                                                    int D) {
  const int row = blockIdx.x;
  const int tid = threadIdx.x;
  __shared__ float s4[4];
  int w0 = norm_quant(in, D, row, tid, s4);
  const int k0 = tid * 4;
  const size_t doff = (size_t)(row >> 4) * (16 * D) + ((k0 >> 6) << 10) +
                      (((k0 >> 4) & 3) << 8) + ((row & 15) << 4) + (k0 & 15);
  *(int*)(out + doff) = w0;
}

// ------- fused i8 GEMM + harmonic-softmax partials — NO LDS, NO BARRIERS ----
// R16 diagnosis: the barrier'd LDS pipeline itself was the floor (~5.4k
// cy/tile vs 1.96k MFMA). Here BOTH operands are fragment-major in global;
// every MFMA operand is one coalesced 1KB global_load_dwordx4 into VGPRs,
// double-buffered one K-tile (BK=128) ahead. No __shared__, no s_barrier,
// no handwritten waitcnt: compiler inserts counted vmcnt before first use
// (the pattern it schedules well, m141/G7). 8 free-running waves/CU
// (2 blocks x 4 waves at launch_bounds(256,2); regs ~215 < 256, margin 40).
// Load latency (L1/L2, ~200-400cy) hides under the same + sibling wave's
// 653cy MFMA block. Waves 2Mx2N: A,B each read twice per block (L1 catches
// part); L2 traffic ~3-4GB over the kernel ≈ 27-35 TB/s < 34.5 ceiling.
__global__ __launch_bounds__(256, 2) void k_gemm_lse(
    const unsigned char* __restrict__ xnb,   // fragment-major A'
    const unsigned char* __restrict__ wnb,   // fragment-major B'
    const int* __restrict__ tgt,
    float* __restrict__ parts,
    float* __restrict__ tlp,
    int M, int C, int D, int ntN) {
  const int ntM = M >> 7;               // 32
  const int nwg = ntM * ntN;            // 8000 (div by 8)
  const int orig = blockIdx.x;
  const int cpx = nwg >> 3;
  const int bid = (orig & 7) * cpx + (orig >> 3);   // bijective XCD swizzle
  const int tileM = bid % ntM;
  const int tileN = bid / ntM;
  const int row0 = tileM << 7;
  const int c0 = tileN << 7;

  const int tid = threadIdx.x;
  const int lane = tid & 63;
  const int wid = tid >> 6;             // 0..3
  const int wr = wid >> 1;              // M-half (64 rows = 4 frags)
  const int wc = wid & 1;               // N-half (64 cols = 4 frags)
  const int fcol = lane & 15;
  const int kq = lane >> 4;
  const int lane16 = lane << 4;

  // fragment-major panel bases: frag f (of 16 rows), k-tile(64) g at
  // base + f*16*D + g*1024 + lane*16
  const size_t fstr = (size_t)(16 * D);
  const unsigned char* apan = xnb + (size_t)(tileM * 8 + wr * 4) * fstr + lane16;
  const unsigned char* bpan = wnb + (size_t)(tileN * 8 + wc * 4) * fstr + lane16;

  i32x4 acc[4][4];
#pragma unroll
  for (int m = 0; m < 4; ++m)
#pragma unroll
    for (int n = 0; n < 4; ++n) acc[m][n] = (i32x4){0, 0, 0, 0};

  i32x4 avA[4][2], avB[4][2], bvA[4][2], bvB[4][2];
  // NT = 8 K-tiles of BK=128 (2 x 64-k frag-columns per tile)

  // prologue: load tile 0 into A-buffers
#pragma unroll
  for (int mm = 0; mm < 4; ++mm)
#pragma unroll
    for (int h = 0; h < 2; ++h) {
      avA[mm][h] = *(const i32x4*)(apan + mm * fstr + h * 1024);
      bvA[mm][h] = *(const i32x4*)(bpan + mm * fstr + h * 1024);
    }

#define TILE(t, CA, CB, NA, NB)                                                \
  do {                                                                         \
    if ((t) + 1 < 8) {                                                         \
      _Pragma("unroll") for (int mm = 0; mm < 4; ++mm)                         \
          _Pragma("unroll") for (int h = 0; h < 2; ++h) {                      \
        NA[mm][h] =                                                            \
            *(const i32x4*)(apan + mm * fstr + (2 * ((t) + 1) + h) * 1024);    \
        NB[mm][h] =                                                            \
            *(const i32x4*)(bpan + mm * fstr + (2 * ((t) + 1) + h) * 1024);    \
      }                                                                        \
    }                                                                          \
    __builtin_amdgcn_s_setprio(1);                                             \
    _Pragma("unroll") for (int mm = 0; mm < 4; ++mm)                           \
        _Pragma("unroll") for (int n = 0; n < 4; ++n)                          \
            _Pragma("unroll") for (int h = 0; h < 2; ++h) acc[mm][n] =         \
                __builtin_amdgcn_mfma_i32_16x16x64_i8(CA[mm][h], CB[n][h],     \
                                                      acc[mm][n], 0, 0, 0);    \
    __builtin_amdgcn_s_setprio(0);                                             \
  } while (0)

  for (int tt = 0; tt < 8; tt += 2) {
    TILE(tt, avA, bvA, avB, bvB);
    TILE(tt + 1, avB, bvB, avA, bvA);
  }

  // ---- epilogue: t2 = 2 - 2*dot/S^2; se-term = t2^-5 = d^-10 ----
  // C/D: col = fcol, row = kq*4 + j per 16x16 fragment. tgt read direct
  // (16 lanes same addr -> broadcast load).
#pragma unroll
  for (int m = 0; m < 4; ++m) {
#pragma unroll
    for (int j = 0; j < 4; ++j) {
      const int rl = wr * 64 + m * 16 + kq * 4 + j;
      const int grow = row0 + rl;
      const int trow = tgt[grow];
      float se = 0.f;
#pragma unroll
      for (int n = 0; n < 4; ++n) {
        float dotf = (float)acc[m][n][j];
        float t2 = fmaxf(fmaf(dotf, -2.f / (QSCALE * QSCALE), 2.f), 1e-6f);
        float r = hw_rcp(t2);
        float r2 = r * r;
        float r4 = r2 * r2;
        se += r4 * r;  // t2^-5
        int col = c0 + wc * 64 + n * 16 + fcol;
        if (col == trow) tlp[grow] = (-HEXP * LN2) * hw_log2(sqrtf(t2) + 1e-8f);
      }
#pragma unroll
      for (int off = 8; off >= 1; off >>= 1) se += __shfl_xor(se, off, 64);
      if (fcol == 0) parts[(size_t)grow * (ntN * 2) + tileN * 2 + wc] = se;
    }
  }
}

// ---------------- per-row sum of linear partials + loss ----------------
__global__ __launch_bounds__(256) void k_combine(const float* __restrict__ parts,
                                                 const float* __restrict__ tlp,
                                                 float* __restrict__ rloss, int P) {
  const int row = blockIdx.x;
  const int tid = threadIdx.x;
  const float* p = parts + (size_t)row * P;
  float s = 0.f;
  for (int i = tid; i < P; i += 256) s += p[i];
#pragma unroll
  for (int off = 32; off >= 1; off >>= 1) s += __shfl_xor(s, off, 64);
  __shared__ float ssum[4];
  if ((tid & 63) == 0) ssum[tid >> 6] = s;
  __syncthreads();
  if (tid == 0) {
    float tot = ssum[0] + ssum[1] + ssum[2] + ssum[3];
    float lse = hw_log2(tot) * LN2;
    float pt = hw_exp2((tlp[row] - lse) * RLN2);
    rloss[row] = -hw_log2(pt + 1e-8f) * LN2;
  }
}

// ---------------- mean over rows ----------------
__global__ __launch_bounds__(256) void k_mean(const float* __restrict__ rloss,
                                              float* __restrict__ out, int B) {
  const int tid = threadIdx.x;
  double s = 0.0;
  for (int i = tid; i < B; i += 256) s += (double)rloss[i];
#pragma unroll
  for (int off = 32; off >= 1; off >>= 1) s += __shfl_xor(s, off, 64);
  __shared__ double sd[4];
  if ((tid & 63) == 0) sd[tid >> 6] = s;
  __syncthreads();
  if (tid == 0) out[0] = (float)((sd[0] + sd[1] + sd[2] + sd[3]) / (double)B);
}

extern "C" void kernel_launch(void* const* d_in, const int* in_sizes, int n_in,
                              void* d_out, int out_size, void* d_ws, size_t ws_size,
                              hipStream_t stream) {
  const float* x = (const float*)d_in[0];
  const float* w = (const float*)d_in[1];
  const int* tg = (const int*)d_in[2];
  const int B = in_sizes[2];
  const int D = in_sizes[0] / B;       // 1024
  const int C = in_sizes[1] / D;       // 32000
  const int ntN = C / 128;             // 250

  char* ws = (char*)d_ws;
  unsigned char* xnb = (unsigned char*)ws;                   // B*D i8 frag-major
  unsigned char* wnb = xnb + (size_t)B * D;                  // C*D i8 frag-major
  size_t off = (size_t)B * D + (size_t)C * D;
  off = (off + 255) & ~(size_t)255;
  float* parts = (float*)(ws + off);                         // B * ntN * 2
  off += (size_t)B * ntN * 2 * sizeof(float);
  float* tlp = (float*)(ws + off);                           // B
  off += (size_t)B * sizeof(float);
  float* rloss = (float*)(ws + off);                         // B

  k_rownorm_fm<<<B, 256, 0, stream>>>(x, xnb, D);
  k_rownorm_fm<<<C, 256, 0, stream>>>(w, wnb, D);
  k_gemm_lse<<<(B / 128) * ntN, 256, 0, stream>>>(xnb, wnb, tg, parts, tlp, B, C, D, ntN);
  k_combine<<<B, 256, 0, stream>>>(parts, tlp, rloss, ntN * 2);
  k_mean<<<1, 256, 0, stream>>>(rloss, (float*)d_out, B);
}

// Round 18
// 225.199 us; speedup vs baseline: 1.3202x; 1.3202x over previous
//
#include <hip/hip_runtime.h>
#include <cstdint>

#define HEXP 10.0f
#define LN2 0.69314718056f
#define RLN2 1.44269504089f
#define QSCALE 500.0f

__device__ __forceinline__ float hw_log2(float x) { return __builtin_amdgcn_logf(x); }
__device__ __forceinline__ float hw_exp2(float x) { return __builtin_amdgcn_exp2f(x); }
__device__ __forceinline__ float hw_rcp(float x) { return __builtin_amdgcn_rcpf(x); }

typedef int i32x4 __attribute__((ext_vector_type(4)));

__device__ __forceinline__ void gl_lds16(const void* g, void* l) {
  __builtin_amdgcn_global_load_lds(
      (const __attribute__((address_space(1))) void*)g,
      (__attribute__((address_space(3))) void*)l, 16, 0, 0);
}

#define BAR() asm volatile("s_barrier" ::: "memory")
#define VM12() asm volatile("s_waitcnt vmcnt(12)" ::: "memory")
#define VM0() asm volatile("s_waitcnt vmcnt(0)" ::: "memory")

// ---- shared normalize+quantize helper (int8, x QSCALE) ----
// |xn_i| <= ~0.17 -> q <= ~87 << 127; dot exact in int32 (<= 7.7M < 2^24).
__device__ __forceinline__ int norm_quant(const float* in, int D, int row,
                                          int tid, float* s4) {
  const float4* inr = (const float4*)(in + (size_t)row * D);
  float4 v = inr[tid];
  float ss = v.x * v.x + v.y * v.y + v.z * v.z + v.w * v.w;
#pragma unroll
  for (int off = 32; off >= 1; off >>= 1) ss += __shfl_xor(ss, off, 64);
  if ((tid & 63) == 0) s4[tid >> 6] = ss;
  __syncthreads();
  float tot = s4[0] + s4[1] + s4[2] + s4[3];
  float scale = QSCALE / fmaxf(sqrtf(tot), 1e-12f);
  int q0 = __float2int_rn(fmaxf(-127.f, fminf(127.f, v.x * scale)));
  int q1 = __float2int_rn(fmaxf(-127.f, fminf(127.f, v.y * scale)));
  int q2 = __float2int_rn(fmaxf(-127.f, fminf(127.f, v.z * scale)));
  int q3 = __float2int_rn(fmaxf(-127.f, fminf(127.f, v.w * scale)));
  return (q0 & 0xff) | ((q1 & 0xff) << 8) | ((q2 & 0xff) << 16) | (q3 << 24);
}

// ------- x rows -> FRAGMENT-MAJOR global A' (R15 verbatim) -------
__global__ __launch_bounds__(256) void k_rownorm_x(const float* __restrict__ in,
                                                   unsigned char* __restrict__ out,
                                                   int D) {
  const int row = blockIdx.x;
  const int tid = threadIdx.x;
  __shared__ float s4[4];
  int w0 = norm_quant(in, D, row, tid, s4);
  const int k0 = tid * 4;
  const size_t doff = (size_t)(row >> 4) * (16 * D) + ((k0 >> 6) << 10) +
                      (((k0 >> 4) & 3) << 8) + ((row & 15) << 4) + (k0 & 15);
  *(int*)(out + doff) = w0;
}

// ------- w rows -> plain row-major (R13 verbatim) -------
__global__ __launch_bounds__(256) void k_rownorm_w(const float* __restrict__ in,
                                                   unsigned char* __restrict__ out,
                                                   int D) {
  const int row = blockIdx.x;
  const int tid = threadIdx.x;
  __shared__ float s4[4];
  int w0 = norm_quant(in, D, row, tid, s4);
  *(int*)(out + (size_t)row * D + tid * 4) = w0;
}

// ------- fused i8 GEMM + harmonic-softmax partials -------
// R16 (best: 187us) + av PREFETCH-AFTER-USE: av(t+1)[mm] loads issued into
// the SAME registers immediately after av(t)[mm]'s last MFMA -> one full tile
// (~1800cy) of flight instead of R16's same-tile ~200cy exposure. Compiler
// inserts per-use vmcnt for av (G7); handwritten cert only covers B staging:
// each body issues exactly 12 VMEM (4 gl_lds + 8 av), so at top of tile t the
// 12-newest = [B(t+1) 4, av(t) 8] and VM12 certifies B(t) count-wise,
// independent of intra-body reorder. Body VM removed. All B machinery
// (zero-conflict layout, rule-#21 staging, ring-3, 3 blocks/CU, setprio,
// XCD swizzle) R16-verbatim.
__global__ __launch_bounds__(256, 3) void k_gemm_lse(
    const unsigned char* __restrict__ xnb,   // fragment-major A'
    const unsigned char* __restrict__ wnb,   // plain row-major
    const int* __restrict__ tgt,
    float* __restrict__ parts,
    float* __restrict__ tlp,
    int M, int C, int D, int ntN) {
  __shared__ __align__(16) unsigned char sB[3][16384];  // 128c x 128k i8
  __shared__ int s_tgt[128];

  const int ntM = M >> 7;               // 32
  const int nwg = ntM * ntN;            // 8000 (div by 8)
  const int orig = blockIdx.x;
  const int cpx = nwg >> 3;
  const int bid = (orig & 7) * cpx + (orig >> 3);   // bijective XCD swizzle
  const int tileM = bid % ntM;
  const int tileN = bid / ntM;
  const int row0 = tileM << 7;
  const int c0 = tileN << 7;

  const int tid = threadIdx.x;
  const int lane = tid & 63;
  const int wid = tid >> 6;             // 0..3
  const int wr = wid >> 1;              // M-half (64 rows)
  const int wc = wid & 1;               // N-half (64 cols)
  const int fcol = lane & 15;
  const int kq = lane >> 4;

  if (tid < 128) s_tgt[tid] = tgt[row0 + tid];

  // B staging lane constants (rule #21 decode, R11/R13 verbatim)
  const int srow_l = lane >> 2;
  const int scol_l = (((lane & 3) ^ ((lane >> 3) & 3)) << 4);
  const int lane16 = lane << 4;
  const size_t Dz = (size_t)D;

#define STAGE_B(ds, sub, kb)                                                   \
  do {                                                                         \
    gl_lds16(wnb + (size_t)(c0 + (wid << 5) + srow_l) * Dz + (kb) + scol_l,    \
             sB[ds] + ((sub) << 13) + (wid << 11) + lane16);                   \
    gl_lds16(wnb + (size_t)(c0 + (wid << 5) + 16 + srow_l) * Dz + (kb) +       \
                 scol_l,                                                       \
             sB[ds] + ((sub) << 13) + (wid << 11) + 1024 + lane16);            \
  } while (0)
#define STAGE_BT(ds, tt) do { STAGE_B(ds, 0, (tt)*128); STAGE_B(ds, 1, (tt)*128 + 64); } while (0)

  // B fragment read base within a sub-chunk (zero-conflict, R11/R13 verbatim)
  const int slot16 = ((kq ^ ((fcol >> 1) & 3)) << 4);
  const int bbase = (wc * 64 + fcol) * 64 + slot16;

  // A' direct-load base (R15 verbatim); 64-k frag f at + f*1024
  const unsigned char* apan =
      xnb + (size_t)(tileM * 8 + wr * 4) * (16 * D) + lane16;

  i32x4 acc[4][4];
#pragma unroll
  for (int m = 0; m < 4; ++m)
#pragma unroll
    for (int n = 0; n < 4; ++n) acc[m][n] = (i32x4){0, 0, 0, 0};

  i32x4 av[4][2], bv[4][2];
  const int NT = D >> 7;  // 8 K-tiles of 128

  // prologue: stage B(0), B(1); issue av(0)
  STAGE_BT(0, 0);
  STAGE_BT(1, 1);
#pragma unroll
  for (int mm = 0; mm < 4; ++mm)
#pragma unroll
    for (int h = 0; h < 2; ++h)
      av[mm][h] = *(const i32x4*)(apan + (size_t)mm * (16 * D) + h * 1024);
  // queue: [B0 4, B1 4, av0 8] = 16 -> VM12 at t=0 certifies B(0).

#pragma unroll
  for (int t = 0; t < 8; ++t) {
    // top cert: 12-newest = [B(t+1) 4, av(t) 8]; everything older (B(t)) done.
    if (t + 1 < NT) VM12();
    else VM0();
    BAR();
    if (t + 2 < NT) STAGE_BT((t + 2) % 3, t + 2);
    {
      const unsigned char* pB_ = sB[t % 3];
#pragma unroll
      for (int n = 0; n < 4; ++n)
#pragma unroll
        for (int h = 0; h < 2; ++h)
          bv[n][h] = *(const i32x4*)(pB_ + (h << 13) + bbase + n * 1024);
    }
    __builtin_amdgcn_s_setprio(1);
#pragma unroll
    for (int mm = 0; mm < 4; ++mm) {
#pragma unroll
      for (int n = 0; n < 4; ++n)
#pragma unroll
        for (int h = 0; h < 2; ++h)
          acc[mm][n] = __builtin_amdgcn_mfma_i32_16x16x64_i8(
              av[mm][h], bv[n][h], acc[mm][n], 0, 0, 0);
      // av[mm] fully consumed -> refill with tile t+1's frags (1-tile flight)
      if (t + 1 < NT) {
#pragma unroll
        for (int h = 0; h < 2; ++h)
          av[mm][h] = *(const i32x4*)(apan + (size_t)mm * (16 * D) +
                                      (2 * (t + 1) + h) * 1024);
      }
    }
    __builtin_amdgcn_s_setprio(0);
  }

  // ---- epilogue: t2 = 2 - 2*dot/S^2; se-term = t2^-5 = d^-10 ----
  // C/D: col = fcol, row = kq*4 + j per 16x16 fragment.
#pragma unroll
  for (int m = 0; m < 4; ++m) {
#pragma unroll
    for (int j = 0; j < 4; ++j) {
      const int rl = wr * 64 + m * 16 + kq * 4 + j;
      const int grow = row0 + rl;
      const int trow = s_tgt[rl];
      float se = 0.f;
#pragma unroll
      for (int n = 0; n < 4; ++n) {
        float dotf = (float)acc[m][n][j];
        float t2 = fmaxf(fmaf(dotf, -2.f / (QSCALE * QSCALE), 2.f), 1e-6f);
        float r = hw_rcp(t2);
        float r2 = r * r;
        float r4 = r2 * r2;
        se += r4 * r;  // t2^-5
        int col = c0 + wc * 64 + n * 16 + fcol;
        if (col == trow) tlp[grow] = (-HEXP * LN2) * hw_log2(sqrtf(t2) + 1e-8f);
      }
#pragma unroll
      for (int off = 8; off >= 1; off >>= 1) se += __shfl_xor(se, off, 64);
      if (fcol == 0) parts[(size_t)grow * (ntN * 2) + tileN * 2 + wc] = se;
    }
  }
}

// ---------------- per-row sum of linear partials + loss ----------------
__global__ __launch_bounds__(256) void k_combine(const float* __restrict__ parts,
                                                 const float* __restrict__ tlp,
                                                 float* __restrict__ rloss, int P) {
  const int row = blockIdx.x;
  const int tid = threadIdx.x;
  const float* p = parts + (size_t)row * P;
  float s = 0.f;
  for (int i = tid; i < P; i += 256) s += p[i];
#pragma unroll
  for (int off = 32; off >= 1; off >>= 1) s += __shfl_xor(s, off, 64);
  __shared__ float ssum[4];
  if ((tid & 63) == 0) ssum[tid >> 6] = s;
  __syncthreads();
  if (tid == 0) {
    float tot = ssum[0] + ssum[1] + ssum[2] + ssum[3];
    float lse = hw_log2(tot) * LN2;
    float pt = hw_exp2((tlp[row] - lse) * RLN2);
    rloss[row] = -hw_log2(pt + 1e-8f) * LN2;
  }
}

// ---------------- mean over rows ----------------
__global__ __launch_bounds__(256) void k_mean(const float* __restrict__ rloss,
                                              float* __restrict__ out, int B) {
  const int tid = threadIdx.x;
  double s = 0.0;
  for (int i = tid; i < B; i += 256) s += (double)rloss[i];
#pragma unroll
  for (int off = 32; off >= 1; off >>= 1) s += __shfl_xor(s, off, 64);
  __shared__ double sd[4];
  if ((tid & 63) == 0) sd[tid >> 6] = s;
  __syncthreads();
  if (tid == 0) out[0] = (float)((sd[0] + sd[1] + sd[2] + sd[3]) / (double)B);
}

extern "C" void kernel_launch(void* const* d_in, const int* in_sizes, int n_in,
                              void* d_out, int out_size, void* d_ws, size_t ws_size,
                              hipStream_t stream) {
  const float* x = (const float*)d_in[0];
  const float* w = (const float*)d_in[1];
  const int* tg = (const int*)d_in[2];
  const int B = in_sizes[2];
  const int D = in_sizes[0] / B;       // 1024
  const int C = in_sizes[1] / D;       // 32000
  const int ntN = C / 128;             // 250

  char* ws = (char*)d_ws;
  unsigned char* xnb = (unsigned char*)ws;                   // B*D i8 (frag-major)
  unsigned char* wnb = xnb + (size_t)B * D;                  // C*D i8 (row-major)
  size_t off = (size_t)B * D + (size_t)C * D;
  off = (off + 255) & ~(size_t)255;
  float* parts = (float*)(ws + off);                         // B * ntN * 2
  off += (size_t)B * ntN * 2 * sizeof(float);
  float* tlp = (float*)(ws + off);                           // B
  off += (size_t)B * sizeof(float);
  float* rloss = (float*)(ws + off);                         // B

  k_rownorm_x<<<B, 256, 0, stream>>>(x, xnb, D);
  k_rownorm_w<<<C, 256, 0, stream>>>(w, wnb, D);
  k_gemm_lse<<<(B / 128) * ntN, 256, 0, stream>>>(xnb, wnb, tg, parts, tlp, B, C, D, ntN);
  k_combine<<<B, 256, 0, stream>>>(parts, tlp, rloss, ntN * 2);
  k_mean<<<1, 256, 0, stream>>>(rloss, (float*)d_out, B);
}

// Round 19
// 222.695 us; speedup vs baseline: 1.3350x; 1.0112x over previous
//
#include <hip/hip_runtime.h>
#include <cstdint>

#define HEXP 10.0f
#define LN2 0.69314718056f
#define RLN2 1.44269504089f
#define QSCALE 500.0f

__device__ __forceinline__ float hw_log2(float x) { return __builtin_amdgcn_logf(x); }
__device__ __forceinline__ float hw_exp2(float x) { return __builtin_amdgcn_exp2f(x); }
__device__ __forceinline__ float hw_rcp(float x) { return __builtin_amdgcn_rcpf(x); }

typedef int i32x4 __attribute__((ext_vector_type(4)));

__device__ __forceinline__ void gl_lds16(const void* g, void* l) {
  __builtin_amdgcn_global_load_lds(
      (const __attribute__((address_space(1))) void*)g,
      (__attribute__((address_space(3))) void*)l, 16, 0, 0);
}

#define BAR() asm volatile("s_barrier" ::: "memory")
#define VM8() asm volatile("s_waitcnt vmcnt(8)" ::: "memory")

// ---- shared normalize+quantize helper (int8, x QSCALE) ----
// |xn_i| <= ~0.17 -> q <= ~87 << 127; dot exact in int32 (<= 7.7M < 2^24).
__device__ __forceinline__ int norm_quant(const float* in, int D, int row,
                                          int tid, float* s4) {
  const float4* inr = (const float4*)(in + (size_t)row * D);
  float4 v = inr[tid];
  float ss = v.x * v.x + v.y * v.y + v.z * v.z + v.w * v.w;
#pragma unroll
  for (int off = 32; off >= 1; off >>= 1) ss += __shfl_xor(ss, off, 64);
  if ((tid & 63) == 0) s4[tid >> 6] = ss;
  __syncthreads();
  float tot = s4[0] + s4[1] + s4[2] + s4[3];
  float scale = QSCALE / fmaxf(sqrtf(tot), 1e-12f);
  int q0 = __float2int_rn(fmaxf(-127.f, fminf(127.f, v.x * scale)));
  int q1 = __float2int_rn(fmaxf(-127.f, fminf(127.f, v.y * scale)));
  int q2 = __float2int_rn(fmaxf(-127.f, fminf(127.f, v.z * scale)));
  int q3 = __float2int_rn(fmaxf(-127.f, fminf(127.f, v.w * scale)));
  return (q0 & 0xff) | ((q1 & 0xff) << 8) | ((q2 & 0xff) << 16) | (q3 << 24);
}

// ------- x rows -> FRAGMENT-MAJOR global A' (R15 verbatim) -------
__global__ __launch_bounds__(256) void k_rownorm_x(const float* __restrict__ in,
                                                   unsigned char* __restrict__ out,
                                                   int D) {
  const int row = blockIdx.x;
  const int tid = threadIdx.x;
  __shared__ float s4[4];
  int w0 = norm_quant(in, D, row, tid, s4);
  const int k0 = tid * 4;
  const size_t doff = (size_t)(row >> 4) * (16 * D) + ((k0 >> 6) << 10) +
                      (((k0 >> 4) & 3) << 8) + ((row & 15) << 4) + (k0 & 15);
  *(int*)(out + doff) = w0;
}

// ------- w rows -> plain row-major (R13 verbatim) -------
__global__ __launch_bounds__(256) void k_rownorm_w(const float* __restrict__ in,
                                                   unsigned char* __restrict__ out,
                                                   int D) {
  const int row = blockIdx.x;
  const int tid = threadIdx.x;
  __shared__ float s4[4];
  int w0 = norm_quant(in, D, row, tid, s4);
  *(int*)(out + (size_t)row * D + tid * 4) = w0;
}

// ------- fused i8 GEMM + harmonic-softmax partials -------
// Tile 128x256, 4 waves (2M x 2N), per-wave 64x128: acc[4][8] = 128 AGPR.
// Figure of merit (R14 lesson) groups x MFMA-per-sync: 2 x 64 = 128 (R16: 96).
// LDS = ring-2 x 32KB B-slots = 64KB -> 2 blocks/CU (2 independent barrier
// groups). Slot = 4 proven zero-conflict 8KB chunks [(colhalf,khalf)], one
// chunk staged entirely by one wave (8 gl_lds, rule-#21 decode verbatim).
//
// Ring-2 calendar (audited): at top of tile t, BAR guarantees slot (t+1)%2's
// readers (tile t-1) are done -> stage B(t+1) there right after BAR. VM8 at
// top certifies B(t): per tile exactly 16 VMEM issue [B(t+1) 8, then av(t+1) 8],
// so the 8-newest at top of t are av(t) -> everything older (B(t)) landed.
// av keeps R18 prefetch-after-use (refill av[mm] after its h=1 last use);
// compiler inserts av/bv per-use waits (G7).
__global__ __launch_bounds__(256, 2) void k_gemm_lse(
    const unsigned char* __restrict__ xnb,   // fragment-major A'
    const unsigned char* __restrict__ wnb,   // plain row-major
    const int* __restrict__ tgt,
    float* __restrict__ parts,
    float* __restrict__ tlp,
    int M, int C, int D, int ntN) {
  __shared__ __align__(16) unsigned char sB[2][32768];  // [slot][colhalf][khalf][8KB]
  __shared__ int s_tgt[128];

  const int ntM = M >> 7;               // 32
  const int nwg = ntM * ntN;            // 4000 (div by 8)
  const int orig = blockIdx.x;
  const int cpx = nwg >> 3;
  const int bid = (orig & 7) * cpx + (orig >> 3);   // bijective XCD swizzle
  const int tileM = bid % ntM;
  const int tileN = bid / ntM;
  const int row0 = tileM << 7;
  const int c0 = tileN << 8;

  const int tid = threadIdx.x;
  const int lane = tid & 63;
  const int wid = tid >> 6;             // 0..3
  const int wr = wid >> 1;              // M-half (64 rows)
  const int wc = wid & 1;               // N-half (128 cols)
  const int fcol = lane & 15;
  const int kq = lane >> 4;

  if (tid < 128) s_tgt[tid] = tgt[row0 + tid];

  // staging lane constants (rule #21 decode, R11/R13 verbatim)
  const int srow_l = lane >> 2;
  const int scol_l = (((lane & 3) ^ ((lane >> 3) & 3)) << 4);
  const int lane16 = lane << 4;
  const size_t Dz = (size_t)D;

  // wave wid stages chunk (colhalf = wid>>1, khalf = wid&1): 8 x 1KB blocks,
  // block q covers B-cols c0 + (wid>>1)*128 + q*16 + srow_l.
#define STAGE_BT(ds, tt)                                                       \
  do {                                                                         \
    _Pragma("unroll") for (int q = 0; q < 8; ++q)                              \
        gl_lds16(wnb + (size_t)(c0 + ((wid >> 1) << 7) + (q << 4) + srow_l) *  \
                           Dz + (tt)*128 + ((wid & 1) << 6) + scol_l,          \
                 sB[ds] + (wid << 13) + (q << 10) + lane16);                   \
  } while (0)

  // bv read: chunk (wc, h) base + (n*16 + fcol)*64 + slot16 (zero-conflict)
  const int slot16 = ((kq ^ ((fcol >> 1) & 3)) << 4);
  const int bbase = fcol * 64 + slot16;

  // A' direct-load base (R15 verbatim); 64-k frag f at + f*1024
  const unsigned char* apan =
      xnb + (size_t)(tileM * 8 + wr * 4) * (16 * D) + lane16;

  i32x4 acc[4][8];
#pragma unroll
  for (int m = 0; m < 4; ++m)
#pragma unroll
    for (int n = 0; n < 8; ++n) acc[m][n] = (i32x4){0, 0, 0, 0};

  i32x4 av[4][2], bv[8];
  const int NT = D >> 7;  // 8 K-tiles of 128

  // prologue: stage B(0) into slot 0; issue av(0). queue = [B0 8, av0 8].
  STAGE_BT(0, 0);
#pragma unroll
  for (int mm = 0; mm < 4; ++mm)
#pragma unroll
    for (int h = 0; h < 2; ++h)
      av[mm][h] = *(const i32x4*)(apan + (size_t)mm * (16 * D) + h * 1024);

#pragma unroll
  for (int t = 0; t < 8; ++t) {
    VM8();   // 8-newest = av(t); certifies B(t) (and B(<t)) for all waves
    BAR();   // cross-wave cert; slot (t+1)&1's readers (tile t-1) done
    if (t + 1 < NT) STAGE_BT((t + 1) & 1, t + 1);
#pragma unroll
    for (int h = 0; h < 2; ++h) {
      const unsigned char* chunk = sB[t & 1] + ((wc * 2 + h) << 13);
#pragma unroll
      for (int n = 0; n < 8; ++n)
        bv[n] = *(const i32x4*)(chunk + (n << 10) + bbase);
      __builtin_amdgcn_s_setprio(1);
#pragma unroll
      for (int mm = 0; mm < 4; ++mm) {
#pragma unroll
        for (int n = 0; n < 8; ++n)
          acc[mm][n] = __builtin_amdgcn_mfma_i32_16x16x64_i8(
              av[mm][h], bv[n], acc[mm][n], 0, 0, 0);
        // after av[mm]'s LAST use (h==1): refill both halves for tile t+1
        if (h == 1 && t + 1 < NT) {
#pragma unroll
          for (int hh = 0; hh < 2; ++hh)
            av[mm][hh] = *(const i32x4*)(apan + (size_t)mm * (16 * D) +
                                         (2 * (t + 1) + hh) * 1024);
        }
      }
      __builtin_amdgcn_s_setprio(0);
    }
  }

  // ---- epilogue: t2 = 2 - 2*dot/S^2; se-term = t2^-5 = d^-10 ----
  // C/D: col = fcol, row = kq*4 + j per 16x16 fragment.
#pragma unroll
  for (int m = 0; m < 4; ++m) {
#pragma unroll
    for (int j = 0; j < 4; ++j) {
      const int rl = wr * 64 + m * 16 + kq * 4 + j;
      const int grow = row0 + rl;
      const int trow = s_tgt[rl];
      float se = 0.f;
#pragma unroll
      for (int n = 0; n < 8; ++n) {
        float dotf = (float)acc[m][n][j];
        float t2 = fmaxf(fmaf(dotf, -2.f / (QSCALE * QSCALE), 2.f), 1e-6f);
        float r = hw_rcp(t2);
        float r2 = r * r;
        float r4 = r2 * r2;
        se += r4 * r;  // t2^-5
        int col = c0 + wc * 128 + n * 16 + fcol;
        if (col == trow) tlp[grow] = (-HEXP * LN2) * hw_log2(sqrtf(t2) + 1e-8f);
      }
#pragma unroll
      for (int off = 8; off >= 1; off >>= 1) se += __shfl_xor(se, off, 64);
      if (fcol == 0) parts[(size_t)grow * (ntN * 2) + tileN * 2 + wc] = se;
    }
  }
}

// ---------------- per-row sum of linear partials + loss ----------------
__global__ __launch_bounds__(256) void k_combine(const float* __restrict__ parts,
                                                 const float* __restrict__ tlp,
                                                 float* __restrict__ rloss, int P) {
  const int row = blockIdx.x;
  const int tid = threadIdx.x;
  const float* p = parts + (size_t)row * P;
  float s = 0.f;
  for (int i = tid; i < P; i += 256) s += p[i];
#pragma unroll
  for (int off = 32; off >= 1; off >>= 1) s += __shfl_xor(s, off, 64);
  __shared__ float ssum[4];
  if ((tid & 63) == 0) ssum[tid >> 6] = s;
  __syncthreads();
  if (tid == 0) {
    float tot = ssum[0] + ssum[1] + ssum[2] + ssum[3];
    float lse = hw_log2(tot) * LN2;
    float pt = hw_exp2((tlp[row] - lse) * RLN2);
    rloss[row] = -hw_log2(pt + 1e-8f) * LN2;
  }
}

// ---------------- mean over rows ----------------
__global__ __launch_bounds__(256) void k_mean(const float* __restrict__ rloss,
                                              float* __restrict__ out, int B) {
  const int tid = threadIdx.x;
  double s = 0.0;
  for (int i = tid; i < B; i += 256) s += (double)rloss[i];
#pragma unroll
  for (int off = 32; off >= 1; off >>= 1) s += __shfl_xor(s, off, 64);
  __shared__ double sd[4];
  if ((tid & 63) == 0) sd[tid >> 6] = s;
  __syncthreads();
  if (tid == 0) out[0] = (float)((sd[0] + sd[1] + sd[2] + sd[3]) / (double)B);
}

extern "C" void kernel_launch(void* const* d_in, const int* in_sizes, int n_in,
                              void* d_out, int out_size, void* d_ws, size_t ws_size,
                              hipStream_t stream) {
  const float* x = (const float*)d_in[0];
  const float* w = (const float*)d_in[1];
  const int* tg = (const int*)d_in[2];
  const int B = in_sizes[2];
  const int D = in_sizes[0] / B;       // 1024
  const int C = in_sizes[1] / D;       // 32000
  const int ntN = C / 256;             // 125

  char* ws = (char*)d_ws;
  unsigned char* xnb = (unsigned char*)ws;                   // B*D i8 (frag-major)
  unsigned char* wnb = xnb + (size_t)B * D;                  // C*D i8 (row-major)
  size_t off = (size_t)B * D + (size_t)C * D;
  off = (off + 255) & ~(size_t)255;
  float* parts = (float*)(ws + off);                         // B * ntN * 2
  off += (size_t)B * ntN * 2 * sizeof(float);
  float* tlp = (float*)(ws + off);                           // B
  off += (size_t)B * sizeof(float);
  float* rloss = (float*)(ws + off);                         // B

  k_rownorm_x<<<B, 256, 0, stream>>>(x, xnb, D);
  k_rownorm_w<<<C, 256, 0, stream>>>(w, wnb, D);
  k_gemm_lse<<<(B / 128) * ntN, 256, 0, stream>>>(xnb, wnb, tg, parts, tlp, B, C, D, ntN);
  k_combine<<<B, 256, 0, stream>>>(parts, tlp, rloss, ntN * 2);
  k_mean<<<1, 256, 0, stream>>>(rloss, (float*)d_out, B);
}